// Round 6
// baseline (161.630 us; speedup 1.0000x reference)
//
#include <hip/hip_runtime.h>
#include <cstddef>

#define T_STEPS 1024
#define BATCH   32768
#define G1      50
#define H1      32
#define G2      20

__device__ __forceinline__ float softplus_f(float x) {
    // jax.nn.softplus = max(x,0) + log1p(exp(-|x|))
    float e = __expf(-fabsf(x));
    return fmaxf(x, 0.0f) + __logf(1.0f + e);
}

// One BLOCK (1 wave, 64 lanes) per time step t. Writes a[t] = dt * beta(t).
__global__ __launch_bounds__(64) void beta_kernel(
    const float* __restrict__ t_steps,
    const float* __restrict__ grid1,      // [50]
    const float* __restrict__ spline_w1,  // [50, 32] (g, j)
    const float* __restrict__ base_w1,    // [32]
    const float* __restrict__ grid2,      // [20]
    const float* __restrict__ spline_w2,  // [640]  index j*20+g
    const float* __restrict__ base_w2,    // [32]
    float* __restrict__ a_out)            // [1024] out: dt*beta
{
    __shared__ float se[G1];
    __shared__ float sh[H1];

    const int t    = blockIdx.x;
    const int lane = threadIdx.x;
    const float x  = t_steps[t];

    if (lane < G1) {
        float d = x - grid1[lane];
        se[lane] = __expf(-10.0f * d * d);
    }
    __syncthreads();

    if (lane < H1) {
        float acc = x * base_w1[lane];
        #pragma unroll
        for (int g = 0; g < G1; ++g)
            acc = fmaf(se[g], spline_w1[g * H1 + lane], acc);  // LDS broadcast
        sh[lane] = acc;
    }
    __syncthreads();

    // layer 2: 640 spline terms, 10 per lane; plus base term for lanes < 32
    float acc = 0.0f;
    #pragma unroll
    for (int k = 0; k < 10; ++k) {
        int p = lane + 64 * k;        // 0..639
        int j = p / G2;
        int g = p - j * G2;
        float d = sh[j] - grid2[g];
        acc = fmaf(__expf(-10.0f * d * d), spline_w2[p], acc);
    }
    if (lane < H1) acc = fmaf(sh[lane], base_w2[lane], acc);

    // 64-lane butterfly reduce
    #pragma unroll
    for (int ofs = 32; ofs >= 1; ofs >>= 1)
        acc += __shfl_xor(acc, ofs, 64);

    if (lane == 0) {
        float dt = t_steps[1] - t_steps[0];
        a_out[t] = dt * softplus_f(acc);
    }
}

// Burst-store scan + NONTEMPORAL stores.
// Evidence so far: R0 (interleaved stores) == R5 (64-deep burst) == 157.6-157.7us
// while R4 (half the waves) = +10us -> store schedule is NOT the limiter at
// 512 waves; scan is at/near a floor. Last candidate mechanism that could hold
// a full-line streaming write below HBM peak *independent of schedule* is L2
// write-back retention (streaming 128 MiB of never-read lines through 32 MiB
// L2). 'nt' stores mark the stream no-reuse. One-line change vs R5; numerics
// identical.
//  - 512 waves (256 blocks x 128 thr, 1 elem/thread) = max TLP for B=32768
//  - per outer iter: compute 64 steps into statically-indexed r[64] (VGPRs),
//    then burst 64 nt dword stores (up to 8 MB in flight across the grid).
__global__ __launch_bounds__(128) void scan_kernel(
    const float* __restrict__ t_steps,
    const float* __restrict__ initial_I,
    const float* __restrict__ gamma_param,
    const float* __restrict__ a_in,   // [1024] dt*beta
    float* __restrict__ out)          // [T, B]
{
    __shared__ float4 sa4[T_STEPS / 4];
    {
        const float4* g4 = (const float4*)a_in;
        #pragma unroll
        for (int i = 0; i < T_STEPS / 4 / 128; ++i)   // 2 iters
            sa4[threadIdx.x + i * 128] = g4[threadIdx.x + i * 128];
    }
    __syncthreads();

    const int b = blockIdx.x * 128 + threadIdx.x;
    float I = initial_I[b];
    float S = 1.0f - I;
    const float gamma = softplus_f(gamma_param[0]);
    const float dt = t_steps[1] - t_steps[0];
    const float c = fmaf(-dt, gamma, 1.0f);   // 1 - dt*gamma
    float* outp = out + b;

    #pragma unroll 1
    for (int tb = 0; tb < T_STEPS; tb += 64) {
        float4 q[16];
        #pragma unroll
        for (int k = 0; k < 16; ++k) q[k] = sa4[tb / 4 + k];
        const float* av = (const float*)q;

        float r[64];                          // staging regs (static idx only)
        #pragma unroll
        for (int k = 0; k < 64; ++k) {
            float a  = av[k];
            float f  = fmaf(a, S, c);        // c + a*S        (uses old S)
            float u  = fmaf(-a, I, 1.0f);    // 1 - a*I        (uses old I)
            float In = I * f;                // I + dt*(b*S*I - g*I)
            float Sn = S * u;                // S - dt*b*S*I
            I = fminf(fmaxf(In, 0.0f), 5.0f);
            S = fminf(fmaxf(Sn, 0.0f), 5.0f);
            r[k] = I;
        }

        #pragma unroll
        for (int k = 0; k < 64; ++k)
            __builtin_nontemporal_store(r[k], &outp[(size_t)(tb + k) * BATCH]);
    }
}

extern "C" void kernel_launch(void* const* d_in, const int* in_sizes, int n_in,
                              void* d_out, int out_size, void* d_ws, size_t ws_size,
                              hipStream_t stream) {
    const float* t_steps     = (const float*)d_in[0];
    const float* initial_I   = (const float*)d_in[1];
    const float* grid1       = (const float*)d_in[2];
    const float* spline_w1   = (const float*)d_in[3];
    const float* base_w1     = (const float*)d_in[4];
    const float* grid2       = (const float*)d_in[5];
    const float* spline_w2   = (const float*)d_in[6];
    const float* base_w2     = (const float*)d_in[7];
    const float* gamma_param = (const float*)d_in[8];
    float* out = (float*)d_out;
    float* a_t = (float*)d_ws;   // 1024 floats: dt*beta(t)

    beta_kernel<<<T_STEPS, 64, 0, stream>>>(
        t_steps, grid1, spline_w1, base_w1, grid2, spline_w2, base_w2, a_t);
    scan_kernel<<<BATCH / 128, 128, 0, stream>>>(
        t_steps, initial_I, gamma_param, a_t, out);
}